// Round 1
// baseline (538.080 us; speedup 1.0000x reference)
//
#include <hip/hip_runtime.h>
#include <hip/hip_bf16.h>

// Problem constants (B, K, D) from the reference.
#define B_SZ 4
#define K_SEQ 4096
#define D_DIM 2048
#define M_ROWS (B_SZ * K_SEQ)   // 16384 rows for the GEMM

// GEMM tile (m97-style): 128x128 block tile, BK=32, 4 waves, each wave 64x64
#define BM 128
#define BN 128
#define BK 32

// Scan chunking: 64 chunks of 64 timesteps
#define CHUNK 64
#define NCHUNK (K_SEQ / CHUNK)   // 64

typedef __attribute__((ext_vector_type(8))) short short8;   // 8 bf16 = 4 VGPRs
typedef __attribute__((ext_vector_type(4))) float floatx4;  // MFMA C/D frag

__device__ __forceinline__ unsigned short f2bf_rne(float f) {
  unsigned int u = __float_as_uint(f);
  u += 0x7fffu + ((u >> 16) & 1u);   // round-to-nearest-even
  return (unsigned short)(u >> 16);
}

// ---- fp32 -> bf16 conversion (vectorized: float4 in, ushort4 out) ----
__global__ void cvt_bf16_kernel(const float* __restrict__ in,
                                unsigned short* __restrict__ out, int n4) {
  int i = blockIdx.x * blockDim.x + threadIdx.x;
  if (i >= n4) return;
  float4 v = ((const float4*)in)[i];
  ushort4 o;
  o.x = f2bf_rne(v.x);
  o.y = f2bf_rne(v.y);
  o.z = f2bf_rne(v.z);
  o.w = f2bf_rne(v.w);
  ((ushort4*)out)[i] = o;
}

// ---- async global->LDS, 16B per lane ----
__device__ __forceinline__ void gl_lds16(const void* g, void* l) {
  __builtin_amdgcn_global_load_lds(
      (const __attribute__((address_space(1))) unsigned int*)g,
      (__attribute__((address_space(3))) unsigned int*)l, 16, 0, 0);
}

// ---- GEMM: lam[m,e] = sigmoid(sum_d x[m,d]*W[e,d] + bias[e]) ----
// A = x_bf16 [M, D_DIM] row-major; Wb = W_bf16 [N=D_DIM, D_DIM] row-major (B^T form)
__global__ __launch_bounds__(256)
void gemm_lam_kernel(const unsigned short* __restrict__ A,
                     const unsigned short* __restrict__ Wb,
                     const float* __restrict__ bias,
                     float* __restrict__ lam) {
  __shared__ __align__(16) unsigned short As[BM * BK];  // 8 KB
  __shared__ __align__(16) unsigned short Bs[BN * BK];  // 8 KB

  const int tid = threadIdx.x;
  const int lane = tid & 63;
  const int wave = tid >> 6;
  const int bm = blockIdx.x * BM;
  const int bn = blockIdx.y * BN;
  const int wr = (wave >> 1) * 64;  // wave row offset within block tile
  const int wc = (wave & 1) * 64;   // wave col offset
  const int lrow = lane & 15;       // row within 16x16 frag (A: m, B: n)
  const int kgrp = lane >> 4;       // k-group: k = kgrp*8 + j

  floatx4 acc[4][4];
#pragma unroll
  for (int i = 0; i < 4; ++i)
#pragma unroll
    for (int j = 0; j < 4; ++j)
      acc[i][j] = (floatx4){0.f, 0.f, 0.f, 0.f};

  // Staging: 128x32 bf16 tile = 512 chunks of 8 bf16 (16B); 256 threads x 2.
  // chunk c -> LDS offset c*8 shorts = row-major [row][32] with row=c>>2.
  const int c0 = tid, c1 = tid + 256;
  const unsigned short* gA0 = A + (size_t)(bm + (c0 >> 2)) * D_DIM + ((c0 & 3) << 3);
  const unsigned short* gA1 = A + (size_t)(bm + (c1 >> 2)) * D_DIM + ((c1 & 3) << 3);
  const unsigned short* gB0 = Wb + (size_t)(bn + (c0 >> 2)) * D_DIM + ((c0 & 3) << 3);
  const unsigned short* gB1 = Wb + (size_t)(bn + (c1 >> 2)) * D_DIM + ((c1 & 3) << 3);
  unsigned short* lA0 = As + c0 * 8;
  unsigned short* lA1 = As + c1 * 8;
  unsigned short* lB0 = Bs + c0 * 8;
  unsigned short* lB1 = Bs + c1 * 8;

  for (int k0 = 0; k0 < D_DIM; k0 += BK) {
    gl_lds16(gA0 + k0, lA0);
    gl_lds16(gA1 + k0, lA1);
    gl_lds16(gB0 + k0, lB0);
    gl_lds16(gB1 + k0, lB1);
    __syncthreads();  // compiler drains vmcnt before s_barrier

    short8 af[4], bf[4];
#pragma unroll
    for (int i = 0; i < 4; ++i) {
      af[i] = *(const short8*)(As + (wr + i * 16 + lrow) * BK + kgrp * 8);
      bf[i] = *(const short8*)(Bs + (wc + i * 16 + lrow) * BK + kgrp * 8);
    }
#pragma unroll
    for (int mi = 0; mi < 4; ++mi)
#pragma unroll
      for (int ni = 0; ni < 4; ++ni)
        acc[mi][ni] = __builtin_amdgcn_mfma_f32_16x16x32_bf16(
            af[mi], bf[ni], acc[mi][ni], 0, 0, 0);
    __syncthreads();  // all reads done before next stage overwrites
  }

  // Epilogue: C/D layout col=lane&15, row=(lane>>4)*4+reg  [m89/m91 verified]
  const int crow = (lane >> 4) << 2;
  const int ccol = lane & 15;
#pragma unroll
  for (int ni = 0; ni < 4; ++ni) {
    const int ge = bn + wc + ni * 16 + ccol;
    const float bb = bias[ge];
#pragma unroll
    for (int mi = 0; mi < 4; ++mi) {
      const int gm0 = bm + wr + mi * 16 + crow;
#pragma unroll
      for (int r = 0; r < 4; ++r) {
        float v = acc[mi][ni][r] + bb;
        lam[(size_t)(gm0 + r) * D_DIM + ge] = 1.0f / (1.0f + __expf(-v));
      }
    }
  }
}

// ---- Scan pass 1: per-(b,chunk,d) affine reduce  s -> A*s + Bv ----
// idx = (b*NCHUNK + c)*D + d ; lanes = consecutive d -> coalesced
__global__ void scan_reduce_kernel(const float* __restrict__ lam,
                                   const float* __restrict__ x,
                                   float* __restrict__ Ach,
                                   float* __restrict__ Bch) {
  int idx = blockIdx.x * blockDim.x + threadIdx.x;
  int d = idx & (D_DIM - 1);
  int c = (idx >> 11) & (NCHUNK - 1);
  int b = idx >> 17;
  size_t base = ((size_t)(b * K_SEQ + c * CHUNK)) * D_DIM + d;
  float Aacc = 1.f, Bv = 0.f;
#pragma unroll 8
  for (int t = 0; t < CHUNK; ++t) {
    size_t o = base + (size_t)t * D_DIM;
    float l = lam[o];
    float u = x[o];
    Aacc *= l;
    Bv = l * Bv + (1.f - l) * u;
  }
  Ach[idx] = Aacc;
  Bch[idx] = Bv;
}

// ---- Scan mid: sequential prefix over chunks per chain (b,d) ----
__global__ void scan_prefix_kernel(const float* __restrict__ Ach,
                                   const float* __restrict__ Bch,
                                   float* __restrict__ Sst) {
  int idx = blockIdx.x * blockDim.x + threadIdx.x;  // < B*D
  int d = idx & (D_DIM - 1);
  int b = idx >> 11;
  float s = 0.f;
#pragma unroll 8
  for (int c = 0; c < NCHUNK; ++c) {
    int o = (b * NCHUNK + c) * D_DIM + d;
    Sst[o] = s;
    s = Ach[o] * s + Bch[o];
  }
}

// ---- Scan pass 2: apply with correct chunk-start state; in-place over lam ----
// lamout aliases lam AND the output: each thread reads lam[o] then overwrites
// the same slot with s -- same-thread read-then-write, no hazard.
__global__ void scan_apply_kernel(float* lamout, const float* __restrict__ x,
                                  const float* __restrict__ Sst) {
  int idx = blockIdx.x * blockDim.x + threadIdx.x;
  int d = idx & (D_DIM - 1);
  int c = (idx >> 11) & (NCHUNK - 1);
  int b = idx >> 17;
  size_t base = ((size_t)(b * K_SEQ + c * CHUNK)) * D_DIM + d;
  float s = Sst[idx];
#pragma unroll 8
  for (int t = 0; t < CHUNK; ++t) {
    size_t o = base + (size_t)t * D_DIM;
    float l = lamout[o];
    float u = x[o];
    s = l * s + (1.f - l) * u;
    lamout[o] = s;
  }
}

extern "C" void kernel_launch(void* const* d_in, const int* in_sizes, int n_in,
                              void* d_out, int out_size, void* d_ws, size_t ws_size,
                              hipStream_t stream) {
  const float* x = (const float*)d_in[0];    // [B,K,D] fp32
  const float* W = (const float*)d_in[1];    // [D,D] fp32
  const float* bias = (const float*)d_in[2]; // [D] fp32
  float* out = (float*)d_out;                // [B,K,D] fp32 (doubles as lam buffer)

  // Workspace layout (bytes):
  //   x_bf16:  67108864  (B*K*D * 2)
  //   W_bf16:   8388608  (D*D * 2)
  //   Ach:      2097152  (B*NCHUNK*D * 4)
  //   Bch:      2097152
  //   Sst:      2097152
  // total ~81.8 MB
  char* ws = (char*)d_ws;
  unsigned short* x_bf = (unsigned short*)ws;
  unsigned short* W_bf = (unsigned short*)(ws + (size_t)67108864);
  float* Ach = (float*)(ws + (size_t)75497472);
  float* Bch = (float*)(ws + (size_t)77594624);
  float* Sst = (float*)(ws + (size_t)79691776);

  // 1) fp32 -> bf16 conversions
  {
    int n4 = M_ROWS * D_DIM / 4;  // 8388608
    cvt_bf16_kernel<<<n4 / 256, 256, 0, stream>>>(x, x_bf, n4);
  }
  {
    int n4 = D_DIM * D_DIM / 4;   // 1048576
    cvt_bf16_kernel<<<n4 / 256, 256, 0, stream>>>(W, W_bf, n4);
  }

  // 2) GEMM + sigmoid epilogue -> lam (stored in d_out)
  {
    dim3 grid(M_ROWS / BM, D_DIM / BN);  // 128 x 16
    gemm_lam_kernel<<<grid, 256, 0, stream>>>(x_bf, W_bf, bias, out);
  }

  // 3) chunked scan: reduce -> prefix -> apply (in-place on d_out)
  {
    int total = B_SZ * NCHUNK * D_DIM;  // 524288
    scan_reduce_kernel<<<total / 256, 256, 0, stream>>>(out, x, Ach, Bch);
    scan_prefix_kernel<<<(B_SZ * D_DIM) / 256, 256, 0, stream>>>(Ach, Bch, Sst);
    scan_apply_kernel<<<total / 256, 256, 0, stream>>>(out, x, Sst);
  }
}

// Round 2
// 484.867 us; speedup vs baseline: 1.1097x; 1.1097x over previous
//
#include <hip/hip_runtime.h>
#include <hip/hip_bf16.h>

// Problem constants (B, K, D) from the reference.
#define B_SZ 4
#define K_SEQ 4096
#define D_DIM 2048
#define M_ROWS (B_SZ * K_SEQ)   // 16384 rows for the GEMM

// GEMM tile (m97-style): 128x128 block tile, BK=32, 4 waves, each wave 64x64
#define BM 128
#define BN 128
#define BK 32

// Scan chunking: 64 chunks of 64 timesteps
#define CHUNK 64
#define NCHUNK (K_SEQ / CHUNK)   // 64

typedef __attribute__((ext_vector_type(8))) short short8;   // 8 bf16 = 4 VGPRs
typedef __attribute__((ext_vector_type(4))) float floatx4;  // MFMA C/D frag

__device__ __forceinline__ unsigned short f2bf_rne(float f) {
  unsigned int u = __float_as_uint(f);
  u += 0x7fffu + ((u >> 16) & 1u);   // round-to-nearest-even
  return (unsigned short)(u >> 16);
}
__device__ __forceinline__ float bf2f(unsigned short u) {
  return __uint_as_float(((unsigned int)u) << 16);
}

// ---- fused fp32 -> bf16 conversion for x and W (one launch) ----
#define NX4 (M_ROWS * D_DIM / 4)   // 8388608 float4s of x
#define NW4 (D_DIM * D_DIM / 4)    // 1048576 float4s of W
__global__ void cvt_bf16_kernel(const float* __restrict__ x,
                                const float* __restrict__ W,
                                unsigned short* __restrict__ xb,
                                unsigned short* __restrict__ Wb) {
  int i = blockIdx.x * blockDim.x + threadIdx.x;
  const float* src;
  unsigned short* dst;
  int j;
  if (i < NX4) { src = x; dst = xb; j = i; }
  else         { src = W; dst = Wb; j = i - NX4; }
  float4 v = ((const float4*)src)[j];
  ushort4 o;
  o.x = f2bf_rne(v.x);
  o.y = f2bf_rne(v.y);
  o.z = f2bf_rne(v.z);
  o.w = f2bf_rne(v.w);
  ((ushort4*)dst)[j] = o;
}

// ---- async global->LDS, 16B per lane ----
__device__ __forceinline__ void gl_lds16(const void* g, void* l) {
  __builtin_amdgcn_global_load_lds(
      (const __attribute__((address_space(1))) unsigned int*)g,
      (__attribute__((address_space(3))) unsigned int*)l, 16, 0, 0);
}

// ---- GEMM: lam[m,e] = sigmoid(sum_d x[m,d]*W[e,d] + bias[e]) ----
// A = x_bf16 [M, D_DIM] row-major; Wb = W_bf16 [N=D_DIM, D_DIM] row-major (B^T form)
//
// LDS layout uses a 16B-chunk XOR swizzle: tile chunk (row, kq), kq=0..3
// (kq = 8-bf16 group within BK=32), is stored at slot  row*4 + (kq ^ f(row)),
// f(row) = (row>>1)&3.  Properties:
//  - the 4 chunks of one row stay inside one 64B LDS block -> the 4 staging
//    lanes of that row still fetch one contiguous 64B global segment
//    (coalescing preserved, global_load_lds dest = base + lane*16 holds);
//  - frag reads: 16 lanes (fixed kq, rows r..r+15) land on chunk-columns
//    (4r + kq^f(r)) mod 8 = each of 8 columns exactly twice = 2 dwords/bank,
//    the b128 optimum (was: 2 columns -> 8-way conflict, 1.7e7 cycles).
__global__ __launch_bounds__(256)
void gemm_lam_kernel(const unsigned short* __restrict__ A,
                     const unsigned short* __restrict__ Wb,
                     const float* __restrict__ bias,
                     float* __restrict__ lam) {
  __shared__ __align__(16) unsigned short As[BM * BK];  // 8 KB
  __shared__ __align__(16) unsigned short Bs[BN * BK];  // 8 KB

  const int tid = threadIdx.x;
  const int lane = tid & 63;
  const int wave = tid >> 6;
  const int bm = blockIdx.x * BM;
  const int bn = blockIdx.y * BN;
  const int wr = (wave >> 1) * 64;  // wave row offset within block tile
  const int wc = (wave & 1) * 64;   // wave col offset
  const int lrow = lane & 15;       // row within 16x16 frag (A: m, B: n)
  const int kgrp = lane >> 4;       // k-group: k = kgrp*8 + j

  floatx4 acc[4][4];
#pragma unroll
  for (int i = 0; i < 4; ++i)
#pragma unroll
    for (int j = 0; j < 4; ++j)
      acc[i][j] = (floatx4){0.f, 0.f, 0.f, 0.f};

  // Staging: 512 chunks of 16B per 128x32 tile; thread stages chunks tid, tid+256.
  // LDS dest = chunk index c; global source = (row = c>>2, kq = (c&3) ^ f(row)).
  const int c0 = tid, c1 = tid + 256;
  const int r0 = c0 >> 2, q0 = (c0 & 3) ^ ((r0 >> 1) & 3);
  const int r1 = c1 >> 2, q1 = (c1 & 3) ^ ((r1 >> 1) & 3);
  const unsigned short* gA0 = A + (size_t)(bm + r0) * D_DIM + (q0 << 3);
  const unsigned short* gA1 = A + (size_t)(bm + r1) * D_DIM + (q1 << 3);
  const unsigned short* gB0 = Wb + (size_t)(bn + r0) * D_DIM + (q0 << 3);
  const unsigned short* gB1 = Wb + (size_t)(bn + r1) * D_DIM + (q1 << 3);
  unsigned short* lA0 = As + c0 * 8;
  unsigned short* lA1 = As + c1 * 8;
  unsigned short* lB0 = Bs + c0 * 8;
  unsigned short* lB1 = Bs + c1 * 8;

  // Frag-read swizzle: row = wr|wc + i*16 + lrow; (row>>1)&3 == (lrow>>1)&3
  // (wr/wc + i*16 are multiples of 16), so the stored-kq is lane-constant:
  const int kq_s = kgrp ^ ((lrow >> 1) & 3);

  for (int k0 = 0; k0 < D_DIM; k0 += BK) {
    gl_lds16(gA0 + k0, lA0);
    gl_lds16(gA1 + k0, lA1);
    gl_lds16(gB0 + k0, lB0);
    gl_lds16(gB1 + k0, lB1);
    __syncthreads();  // compiler drains vmcnt before s_barrier

    short8 af[4], bf[4];
#pragma unroll
    for (int i = 0; i < 4; ++i) {
      const int rowA = wr + i * 16 + lrow;
      const int rowB = wc + i * 16 + lrow;
      af[i] = *(const short8*)(As + rowA * 32 + kq_s * 8);
      bf[i] = *(const short8*)(Bs + rowB * 32 + kq_s * 8);
    }
#pragma unroll
    for (int mi = 0; mi < 4; ++mi)
#pragma unroll
      for (int ni = 0; ni < 4; ++ni)
        acc[mi][ni] = __builtin_amdgcn_mfma_f32_16x16x32_bf16(
            af[mi], bf[ni], acc[mi][ni], 0, 0, 0);
    __syncthreads();  // all reads done before next stage overwrites
  }

  // Epilogue: C/D layout col=lane&15, row=(lane>>4)*4+reg  [m89/m91 verified]
  const int crow = (lane >> 4) << 2;
  const int ccol = lane & 15;
#pragma unroll
  for (int ni = 0; ni < 4; ++ni) {
    const int ge = bn + wc + ni * 16 + ccol;
    const float bb = bias[ge];
#pragma unroll
    for (int mi = 0; mi < 4; ++mi) {
      const int gm0 = bm + wr + mi * 16 + crow;
#pragma unroll
      for (int r = 0; r < 4; ++r) {
        float v = acc[mi][ni][r] + bb;
        lam[(size_t)(gm0 + r) * D_DIM + ge] = 1.0f / (1.0f + __expf(-v));
      }
    }
  }
}

// ---- Scan pass 1: per-(b,chunk,d4) affine reduce, float4/lane ----
// idx over B*NCHUNK*(D/4); lanes = consecutive d4 -> 16B/lane coalesced.
// u comes from x_bf16 (8B/lane) -- halves x traffic; error ~2^-9 * |u|.
__global__ void scan_reduce_kernel(const float* __restrict__ lam,
                                   const unsigned short* __restrict__ xb,
                                   float* __restrict__ Ach,
                                   float* __restrict__ Bch) {
  int idx = blockIdx.x * blockDim.x + threadIdx.x;
  int d4 = idx & (D_DIM / 4 - 1);        // 0..511
  int c = (idx >> 9) & (NCHUNK - 1);
  int b = idx >> 15;
  size_t base = ((size_t)(b * K_SEQ + c * CHUNK)) * D_DIM + d4 * 4;
  float4 Aacc = make_float4(1.f, 1.f, 1.f, 1.f);
  float4 Bv = make_float4(0.f, 0.f, 0.f, 0.f);
#pragma unroll 4
  for (int t = 0; t < CHUNK; ++t) {
    size_t o = base + (size_t)t * D_DIM;
    float4 l = *(const float4*)(lam + o);
    ushort4 ub = *(const ushort4*)(xb + o);
    // s' = l*s + (1-l)*u  ==  l*(s-u) + u
    Aacc.x *= l.x; Bv.x = l.x * (Bv.x - bf2f(ub.x)) + bf2f(ub.x);
    Aacc.y *= l.y; Bv.y = l.y * (Bv.y - bf2f(ub.y)) + bf2f(ub.y);
    Aacc.z *= l.z; Bv.z = l.z * (Bv.z - bf2f(ub.z)) + bf2f(ub.z);
    Aacc.w *= l.w; Bv.w = l.w * (Bv.w - bf2f(ub.w)) + bf2f(ub.w);
  }
  ((float4*)Ach)[idx] = Aacc;   // element layout (b*NCHUNK+c)*D + d4*4
  ((float4*)Bch)[idx] = Bv;
}

// ---- Scan mid: sequential prefix over chunks per chain (b, d4) ----
__global__ void scan_prefix_kernel(const float* __restrict__ Ach,
                                   const float* __restrict__ Bch,
                                   float* __restrict__ Sst) {
  int idx = blockIdx.x * blockDim.x + threadIdx.x;  // < B*D/4 = 2048
  int d4 = idx & (D_DIM / 4 - 1);
  int b = idx >> 9;
  float4 s = make_float4(0.f, 0.f, 0.f, 0.f);
#pragma unroll 4
  for (int c = 0; c < NCHUNK; ++c) {
    int o4 = (b * NCHUNK + c) * (D_DIM / 4) + d4;
    ((float4*)Sst)[o4] = s;
    float4 A = ((const float4*)Ach)[o4];
    float4 Bv = ((const float4*)Bch)[o4];
    s.x = A.x * s.x + Bv.x;
    s.y = A.y * s.y + Bv.y;
    s.z = A.z * s.z + Bv.z;
    s.w = A.w * s.w + Bv.w;
  }
}

// ---- Scan pass 2: apply with chunk-start state; in-place over lam ----
// lamout aliases lam AND the output: each thread reads lam[o] then overwrites
// the same slot with s -- same-thread read-then-write, no hazard.
__global__ void scan_apply_kernel(float* lamout,
                                  const unsigned short* __restrict__ xb,
                                  const float* __restrict__ Sst) {
  int idx = blockIdx.x * blockDim.x + threadIdx.x;
  int d4 = idx & (D_DIM / 4 - 1);
  int c = (idx >> 9) & (NCHUNK - 1);
  int b = idx >> 15;
  size_t base = ((size_t)(b * K_SEQ + c * CHUNK)) * D_DIM + d4 * 4;
  float4 s = ((const float4*)Sst)[idx];
#pragma unroll 4
  for (int t = 0; t < CHUNK; ++t) {
    size_t o = base + (size_t)t * D_DIM;
    float4 l = *(const float4*)(lamout + o);
    ushort4 ub = *(const ushort4*)(xb + o);
    s.x = l.x * (s.x - bf2f(ub.x)) + bf2f(ub.x);
    s.y = l.y * (s.y - bf2f(ub.y)) + bf2f(ub.y);
    s.z = l.z * (s.z - bf2f(ub.z)) + bf2f(ub.z);
    s.w = l.w * (s.w - bf2f(ub.w)) + bf2f(ub.w);
    *(float4*)(lamout + o) = s;
  }
}

extern "C" void kernel_launch(void* const* d_in, const int* in_sizes, int n_in,
                              void* d_out, int out_size, void* d_ws, size_t ws_size,
                              hipStream_t stream) {
  const float* x = (const float*)d_in[0];    // [B,K,D] fp32
  const float* W = (const float*)d_in[1];    // [D,D] fp32
  const float* bias = (const float*)d_in[2]; // [D] fp32
  float* out = (float*)d_out;                // [B,K,D] fp32 (doubles as lam buffer)

  // Workspace layout (bytes):
  //   x_bf16:  67108864  (B*K*D * 2)
  //   W_bf16:   8388608  (D*D * 2)
  //   Ach:      2097152  (B*NCHUNK*D * 4)
  //   Bch:      2097152
  //   Sst:      2097152
  // total ~81.8 MB
  char* ws = (char*)d_ws;
  unsigned short* x_bf = (unsigned short*)ws;
  unsigned short* W_bf = (unsigned short*)(ws + (size_t)67108864);
  float* Ach = (float*)(ws + (size_t)75497472);
  float* Bch = (float*)(ws + (size_t)77594624);
  float* Sst = (float*)(ws + (size_t)79691776);

  // 1) fp32 -> bf16 conversions (x and W in one launch)
  cvt_bf16_kernel<<<(NX4 + NW4) / 256, 256, 0, stream>>>(x, W, x_bf, W_bf);

  // 2) GEMM + sigmoid epilogue -> lam (stored in d_out)
  {
    dim3 grid(M_ROWS / BM, D_DIM / BN);  // 128 x 16
    gemm_lam_kernel<<<grid, 256, 0, stream>>>(x_bf, W_bf, bias, out);
  }

  // 3) chunked scan: reduce -> prefix -> apply (in-place on d_out)
  {
    int total4 = B_SZ * NCHUNK * D_DIM / 4;  // 131072
    scan_reduce_kernel<<<total4 / 256, 256, 0, stream>>>(out, x_bf, Ach, Bch);
    scan_prefix_kernel<<<(B_SZ * D_DIM / 4) / 256, 256, 0, stream>>>(Ach, Bch, Sst);
    scan_apply_kernel<<<total4 / 256, 256, 0, stream>>>(out, x_bf, Sst);
  }
}

// Round 3
// 478.226 us; speedup vs baseline: 1.1252x; 1.0139x over previous
//
#include <hip/hip_runtime.h>
#include <hip/hip_bf16.h>

// Problem constants (B, K, D) from the reference.
#define B_SZ 4
#define K_SEQ 4096
#define D_DIM 2048
#define M_ROWS (B_SZ * K_SEQ)   // 16384 rows for the GEMM

// GEMM tile (m97-style): 128x128 block tile, BK=32, 4 waves, each wave 64x64
#define BM 128
#define BN 128
#define BK 32

// Scan chunking: 64 chunks of 64 timesteps
#define CHUNK 64
#define NCHUNK (K_SEQ / CHUNK)   // 64

typedef __attribute__((ext_vector_type(8))) short short8;   // 8 bf16 = 4 VGPRs
typedef __attribute__((ext_vector_type(4))) float floatx4;  // MFMA C/D frag
typedef __attribute__((ext_vector_type(8))) unsigned short ushortx8;

__device__ __forceinline__ unsigned short f2bf_rne(float f) {
  unsigned int u = __float_as_uint(f);
  u += 0x7fffu + ((u >> 16) & 1u);   // round-to-nearest-even
  return (unsigned short)(u >> 16);
}
__device__ __forceinline__ float bf2f(unsigned short u) {
  return __uint_as_float(((unsigned int)u) << 16);
}

// ---- fused fp32 -> bf16 conversion for x and W (one launch) ----
#define NX4 (M_ROWS * D_DIM / 4)   // 8388608 float4s of x
#define NW4 (D_DIM * D_DIM / 4)    // 1048576 float4s of W
__global__ void cvt_bf16_kernel(const float* __restrict__ x,
                                const float* __restrict__ W,
                                unsigned short* __restrict__ xb,
                                unsigned short* __restrict__ Wb) {
  int i = blockIdx.x * blockDim.x + threadIdx.x;
  const float* src;
  unsigned short* dst;
  int j;
  if (i < NX4) { src = x; dst = xb; j = i; }
  else         { src = W; dst = Wb; j = i - NX4; }
  float4 v = ((const float4*)src)[j];
  ushort4 o;
  o.x = f2bf_rne(v.x);
  o.y = f2bf_rne(v.y);
  o.z = f2bf_rne(v.z);
  o.w = f2bf_rne(v.w);
  ((ushort4*)dst)[j] = o;
}

// ---- async global->LDS, 16B per lane ----
__device__ __forceinline__ void gl_lds16(const void* g, void* l) {
  __builtin_amdgcn_global_load_lds(
      (const __attribute__((address_space(1))) unsigned int*)g,
      (__attribute__((address_space(3))) unsigned int*)l, 16, 0, 0);
}

// ---- GEMM: v[m,e] = sum_d x[m,d]*W[e,d] + bias[e] ----
// GBF=true : stores gamma = sigmoid(-v) = 1-lambda as bf16 (numerically safe:
//            error 2^-9*gamma is NOT amplified by long memory, unlike bf16 lambda).
// GBF=false: stores lambda = sigmoid(v) as fp32 (fallback path, R2 semantics).
// LDS 16B-chunk XOR swizzle (R2): chunk (row,kq) at slot row*4 + (kq ^ ((row>>1)&3)).
// Conflicts measured 0 with this layout.
template <bool GBF>
__global__ __launch_bounds__(256)
void gemm_lam_kernel(const unsigned short* __restrict__ A,
                     const unsigned short* __restrict__ Wb,
                     const float* __restrict__ bias,
                     void* __restrict__ lamv) {
  __shared__ __align__(16) unsigned short As[BM * BK];  // 8 KB
  __shared__ __align__(16) unsigned short Bs[BN * BK];  // 8 KB

  const int tid = threadIdx.x;
  const int lane = tid & 63;
  const int wave = tid >> 6;
  const int bm = blockIdx.x * BM;
  const int bn = blockIdx.y * BN;
  const int wr = (wave >> 1) * 64;  // wave row offset within block tile
  const int wc = (wave & 1) * 64;   // wave col offset
  const int lrow = lane & 15;       // row within 16x16 frag (A: m, B: n)
  const int kgrp = lane >> 4;       // k-group: k = kgrp*8 + j

  floatx4 acc[4][4];
#pragma unroll
  for (int i = 0; i < 4; ++i)
#pragma unroll
    for (int j = 0; j < 4; ++j)
      acc[i][j] = (floatx4){0.f, 0.f, 0.f, 0.f};

  const int c0 = tid, c1 = tid + 256;
  const int r0 = c0 >> 2, q0 = (c0 & 3) ^ ((r0 >> 1) & 3);
  const int r1 = c1 >> 2, q1 = (c1 & 3) ^ ((r1 >> 1) & 3);
  const unsigned short* gA0 = A + (size_t)(bm + r0) * D_DIM + (q0 << 3);
  const unsigned short* gA1 = A + (size_t)(bm + r1) * D_DIM + (q1 << 3);
  const unsigned short* gB0 = Wb + (size_t)(bn + r0) * D_DIM + (q0 << 3);
  const unsigned short* gB1 = Wb + (size_t)(bn + r1) * D_DIM + (q1 << 3);
  unsigned short* lA0 = As + c0 * 8;
  unsigned short* lA1 = As + c1 * 8;
  unsigned short* lB0 = Bs + c0 * 8;
  unsigned short* lB1 = Bs + c1 * 8;

  const int kq_s = kgrp ^ ((lrow >> 1) & 3);

  for (int k0 = 0; k0 < D_DIM; k0 += BK) {
    gl_lds16(gA0 + k0, lA0);
    gl_lds16(gA1 + k0, lA1);
    gl_lds16(gB0 + k0, lB0);
    gl_lds16(gB1 + k0, lB1);
    __syncthreads();

    short8 af[4], bf[4];
#pragma unroll
    for (int i = 0; i < 4; ++i) {
      const int rowA = wr + i * 16 + lrow;
      const int rowB = wc + i * 16 + lrow;
      af[i] = *(const short8*)(As + rowA * 32 + kq_s * 8);
      bf[i] = *(const short8*)(Bs + rowB * 32 + kq_s * 8);
    }
#pragma unroll
    for (int mi = 0; mi < 4; ++mi)
#pragma unroll
      for (int ni = 0; ni < 4; ++ni)
        acc[mi][ni] = __builtin_amdgcn_mfma_f32_16x16x32_bf16(
            af[mi], bf[ni], acc[mi][ni], 0, 0, 0);
    __syncthreads();
  }

  // Epilogue: C/D layout col=lane&15, row=(lane>>4)*4+reg  [m89/m91 verified]
  const int crow = (lane >> 4) << 2;
  const int ccol = lane & 15;
#pragma unroll
  for (int ni = 0; ni < 4; ++ni) {
    const int ge = bn + wc + ni * 16 + ccol;
    const float bb = bias[ge];
#pragma unroll
    for (int mi = 0; mi < 4; ++mi) {
      const int gm0 = bm + wr + mi * 16 + crow;
#pragma unroll
      for (int r = 0; r < 4; ++r) {
        float v = acc[mi][ni][r] + bb;
        size_t off = (size_t)(gm0 + r) * D_DIM + ge;
        if constexpr (GBF) {
          // gamma = 1 - sigmoid(v) = sigmoid(-v) = 1/(1+e^v)
          float g = 1.0f / (1.0f + __expf(v));
          ((unsigned short*)lamv)[off] = f2bf_rne(g);
        } else {
          ((float*)lamv)[off] = 1.0f / (1.0f + __expf(-v));
        }
      }
    }
  }
}

// ======================= bf16-gamma scan path ============================
// Recurrence with gamma: s_t = s_{t-1} + g_t*(u_t - s_{t-1});  A-factor = (1-g).

// Pass 1: per-(b,chunk,d8) affine reduce, 16B/lane dual streams.
__global__ void scan_reduce_bf(const unsigned short* __restrict__ gb,
                               const unsigned short* __restrict__ xb,
                               float* __restrict__ Ach,
                               float* __restrict__ Bch) {
  int idx = blockIdx.x * blockDim.x + threadIdx.x;  // < 65536
  int d8 = idx & 255;
  int c = (idx >> 8) & (NCHUNK - 1);
  int b = idx >> 14;
  size_t base = ((size_t)(b * K_SEQ + c * CHUNK)) * D_DIM + d8 * 8;
  float A[8], Bv[8];
#pragma unroll
  for (int j = 0; j < 8; ++j) { A[j] = 1.f; Bv[j] = 0.f; }
#pragma unroll 8
  for (int t = 0; t < CHUNK; ++t) {
    size_t o = base + (size_t)t * D_DIM;
    ushortx8 g8 = *(const ushortx8*)(gb + o);
    ushortx8 u8 = *(const ushortx8*)(xb + o);
#pragma unroll
    for (int j = 0; j < 8; ++j) {
      float g = bf2f(g8[j]), u = bf2f(u8[j]);
      A[j] -= g * A[j];          // A *= (1-g)
      Bv[j] += g * (u - Bv[j]);  // B = (1-g)B + g*u
    }
  }
  float4 a0 = make_float4(A[0], A[1], A[2], A[3]);
  float4 a1 = make_float4(A[4], A[5], A[6], A[7]);
  float4 b0 = make_float4(Bv[0], Bv[1], Bv[2], Bv[3]);
  float4 b1 = make_float4(Bv[4], Bv[5], Bv[6], Bv[7]);
  ((float4*)Ach)[idx * 2] = a0;
  ((float4*)Ach)[idx * 2 + 1] = a1;
  ((float4*)Bch)[idx * 2] = b0;
  ((float4*)Bch)[idx * 2 + 1] = b1;
}

// Mid pass: sequential prefix over chunks per chain (b, d4). fp32, unchanged.
__global__ void scan_prefix_kernel(const float* __restrict__ Ach,
                                   const float* __restrict__ Bch,
                                   float* __restrict__ Sst) {
  int idx = blockIdx.x * blockDim.x + threadIdx.x;  // < B*D/4 = 2048
  int d4 = idx & (D_DIM / 4 - 1);
  int b = idx >> 9;
  float4 s = make_float4(0.f, 0.f, 0.f, 0.f);
#pragma unroll 4
  for (int c = 0; c < NCHUNK; ++c) {
    int o4 = (b * NCHUNK + c) * (D_DIM / 4) + d4;
    ((float4*)Sst)[o4] = s;
    float4 A = ((const float4*)Ach)[o4];
    float4 Bv = ((const float4*)Bch)[o4];
    s.x = A.x * s.x + Bv.x;
    s.y = A.y * s.y + Bv.y;
    s.z = A.z * s.z + Bv.z;
    s.w = A.w * s.w + Bv.w;
  }
}

// Pass 2: apply with chunk-start state; writes fp32 output.
__global__ void scan_apply_bf(const unsigned short* __restrict__ gb,
                              const unsigned short* __restrict__ xb,
                              const float* __restrict__ Sst,
                              float* __restrict__ out) {
  int idx = blockIdx.x * blockDim.x + threadIdx.x;  // < 65536
  int d8 = idx & 255;
  int c = (idx >> 8) & (NCHUNK - 1);
  int b = idx >> 14;
  size_t base = ((size_t)(b * K_SEQ + c * CHUNK)) * D_DIM + d8 * 8;
  float4 s0 = ((const float4*)Sst)[idx * 2];
  float4 s1 = ((const float4*)Sst)[idx * 2 + 1];
  float s[8] = {s0.x, s0.y, s0.z, s0.w, s1.x, s1.y, s1.z, s1.w};
#pragma unroll 8
  for (int t = 0; t < CHUNK; ++t) {
    size_t o = base + (size_t)t * D_DIM;
    ushortx8 g8 = *(const ushortx8*)(gb + o);
    ushortx8 u8 = *(const ushortx8*)(xb + o);
#pragma unroll
    for (int j = 0; j < 8; ++j) {
      float g = bf2f(g8[j]), u = bf2f(u8[j]);
      s[j] += g * (u - s[j]);
    }
    *(float4*)(out + o) = make_float4(s[0], s[1], s[2], s[3]);
    *(float4*)(out + o + 4) = make_float4(s[4], s[5], s[6], s[7]);
  }
}

// ======================= fp32-lambda fallback path =======================
__global__ void scan_reduce_kernel(const float* __restrict__ lam,
                                   const unsigned short* __restrict__ xb,
                                   float* __restrict__ Ach,
                                   float* __restrict__ Bch) {
  int idx = blockIdx.x * blockDim.x + threadIdx.x;
  int d4 = idx & (D_DIM / 4 - 1);
  int c = (idx >> 9) & (NCHUNK - 1);
  int b = idx >> 15;
  size_t base = ((size_t)(b * K_SEQ + c * CHUNK)) * D_DIM + d4 * 4;
  float4 Aacc = make_float4(1.f, 1.f, 1.f, 1.f);
  float4 Bv = make_float4(0.f, 0.f, 0.f, 0.f);
#pragma unroll 4
  for (int t = 0; t < CHUNK; ++t) {
    size_t o = base + (size_t)t * D_DIM;
    float4 l = *(const float4*)(lam + o);
    ushort4 ub = *(const ushort4*)(xb + o);
    Aacc.x *= l.x; Bv.x = l.x * (Bv.x - bf2f(ub.x)) + bf2f(ub.x);
    Aacc.y *= l.y; Bv.y = l.y * (Bv.y - bf2f(ub.y)) + bf2f(ub.y);
    Aacc.z *= l.z; Bv.z = l.z * (Bv.z - bf2f(ub.z)) + bf2f(ub.z);
    Aacc.w *= l.w; Bv.w = l.w * (Bv.w - bf2f(ub.w)) + bf2f(ub.w);
  }
  ((float4*)Ach)[idx] = Aacc;
  ((float4*)Bch)[idx] = Bv;
}

__global__ void scan_apply_kernel(float* lamout,
                                  const unsigned short* __restrict__ xb,
                                  const float* __restrict__ Sst) {
  int idx = blockIdx.x * blockDim.x + threadIdx.x;
  int d4 = idx & (D_DIM / 4 - 1);
  int c = (idx >> 9) & (NCHUNK - 1);
  int b = idx >> 15;
  size_t base = ((size_t)(b * K_SEQ + c * CHUNK)) * D_DIM + d4 * 4;
  float4 s = ((const float4*)Sst)[idx];
#pragma unroll 4
  for (int t = 0; t < CHUNK; ++t) {
    size_t o = base + (size_t)t * D_DIM;
    float4 l = *(const float4*)(lamout + o);
    ushort4 ub = *(const ushort4*)(xb + o);
    s.x = l.x * (s.x - bf2f(ub.x)) + bf2f(ub.x);
    s.y = l.y * (s.y - bf2f(ub.y)) + bf2f(ub.y);
    s.z = l.z * (s.z - bf2f(ub.z)) + bf2f(ub.z);
    s.w = l.w * (s.w - bf2f(ub.w)) + bf2f(ub.w);
    *(float4*)(lamout + o) = s;
  }
}

extern "C" void kernel_launch(void* const* d_in, const int* in_sizes, int n_in,
                              void* d_out, int out_size, void* d_ws, size_t ws_size,
                              hipStream_t stream) {
  const float* x = (const float*)d_in[0];    // [B,K,D] fp32
  const float* W = (const float*)d_in[1];    // [D,D] fp32
  const float* bias = (const float*)d_in[2]; // [D] fp32
  float* out = (float*)d_out;                // [B,K,D] fp32

  char* ws = (char*)d_ws;
  // bf16-gamma path workspace:
  //   x_bf  67108864 | W_bf 8388608 | g_bf 67108864 | Ach/Bch/Sst 3x2097152
  const size_t NEED_BF = 148897792ULL;
  const bool bfpath = (ws_size >= NEED_BF);  // constant per process -> capture-safe

  unsigned short* x_bf = (unsigned short*)ws;
  unsigned short* W_bf = (unsigned short*)(ws + 67108864ULL);

  // 1) fp32 -> bf16 conversions (x and W in one launch)
  cvt_bf16_kernel<<<(NX4 + NW4) / 256, 256, 0, stream>>>(x, W, x_bf, W_bf);

  if (bfpath) {
    unsigned short* g_bf = (unsigned short*)(ws + 75497472ULL);
    float* Ach = (float*)(ws + 142606336ULL);
    float* Bch = (float*)(ws + 144703488ULL);
    float* Sst = (float*)(ws + 146800640ULL);

    dim3 grid(M_ROWS / BM, D_DIM / BN);
    gemm_lam_kernel<true><<<grid, 256, 0, stream>>>(x_bf, W_bf, bias, g_bf);

    int total8 = B_SZ * NCHUNK * D_DIM / 8;  // 65536
    scan_reduce_bf<<<total8 / 256, 256, 0, stream>>>(g_bf, x_bf, Ach, Bch);
    scan_prefix_kernel<<<(B_SZ * D_DIM / 4) / 256, 256, 0, stream>>>(Ach, Bch, Sst);
    scan_apply_bf<<<total8 / 256, 256, 0, stream>>>(g_bf, x_bf, Sst, out);
  } else {
    // fallback: lambda fp32 in d_out, in-place apply (R2 layout, ws >= 82 MB)
    float* Ach = (float*)(ws + 75497472ULL);
    float* Bch = (float*)(ws + 77594624ULL);
    float* Sst = (float*)(ws + 79691776ULL);

    dim3 grid(M_ROWS / BM, D_DIM / BN);
    gemm_lam_kernel<false><<<grid, 256, 0, stream>>>(x_bf, W_bf, bias, out);

    int total4 = B_SZ * NCHUNK * D_DIM / 4;  // 131072
    scan_reduce_kernel<<<total4 / 256, 256, 0, stream>>>(out, x_bf, Ach, Bch);
    scan_prefix_kernel<<<(B_SZ * D_DIM / 4) / 256, 256, 0, stream>>>(Ach, Bch, Sst);
    scan_apply_kernel<<<total4 / 256, 256, 0, stream>>>(out, x_bf, Sst);
  }
}